// Round 2
// baseline (2488.096 us; speedup 1.0000x reference)
//
#include <hip/hip_runtime.h>
#include <stdint.h>
#include <math.h>

// ---------------- problem constants ----------------
#define P_     4
#define L_     32
#define H_     1024
#define NE_    132          // (L_+1)*P_ embedding vectors
#define G4_    4096         // 4*H
#define TEMP_  5.0f
#define TANHC_ 2.5f
#define TINY_  1.1754943508222875e-38f   // jnp.finfo(f32).tiny

// JAX >= 0.4.36 defaults to threefry_partitionable=True
#define PRNG_PARTITIONABLE 1

// ---------------- device helpers ----------------
__device__ __forceinline__ float wave_reduce_sum(float v) {
  for (int off = 32; off; off >>= 1) v += __shfl_xor(v, off);
  return v;
}

__device__ __forceinline__ float sigmoidf_(float x) {
  // XLA lowers logistic via tanh: 0.5 + 0.5*tanh(0.5x)
  return 0.5f + 0.5f * tanhf(0.5f * x);
}

// Threefry-2x32, 20 rounds (JAX reference implementation structure)
__device__ __forceinline__ void tf2x32(uint32_t k0, uint32_t k1,
                                       uint32_t& x0, uint32_t& x1) {
  uint32_t ks2 = k0 ^ k1 ^ 0x1BD11BDAu;
  x0 += k0; x1 += k1;
#define RR(r) { x0 += x1; x1 = (x1 << r) | (x1 >> (32 - r)); x1 ^= x0; }
  RR(13) RR(15) RR(26) RR(6)
  x0 += k1;  x1 += ks2 + 1u;
  RR(17) RR(29) RR(16) RR(24)
  x0 += ks2; x1 += k0 + 2u;
  RR(13) RR(15) RR(26) RR(6)
  x0 += k0;  x1 += k1 + 3u;
  RR(17) RR(29) RR(16) RR(24)
  x0 += k1;  x1 += ks2 + 4u;
  RR(13) RR(15) RR(26) RR(6)
  x0 += ks2; x1 += k0 + 5u;
#undef RR
}

// ---------------- kernels ----------------

__global__ void k_init(float* scalars, int* idx_buf) {
  if (threadIdx.x == 0) { scalars[0] = 0.f; scalars[1] = 0.f; *idx_buf = 0; }
}

// Xp[p][e][r] = W_ih[p][r] . emb[e] + b_ih[p][r] + b_hh[p][r]
// grid 1024 blocks x 256 thr; block -> (p, 16-row group); wave -> 4 rows, W in regs.
__global__ __launch_bounds__(256) void k_pre(const float* __restrict__ emb,
                                             const float* __restrict__ w_ih,
                                             const float* __restrict__ b_ih,
                                             const float* __restrict__ b_hh,
                                             float* __restrict__ Xp) {
  int blk  = blockIdx.x;
  int p    = blk >> 8;        // 256 row-groups per path
  int rg   = blk & 255;
  int wave = threadIdx.x >> 6;
  int lane = threadIdx.x & 63;
  int r0   = rg * 16 + wave * 4;

  const float* wbase = w_ih + ((size_t)p * G4_ + r0) * H_;
  float4 Wr[4][4];
  for (int q = 0; q < 4; ++q)
    for (int it = 0; it < 4; ++it)
      Wr[q][it] = *(const float4*)(wbase + (size_t)q * H_ + lane * 4 + it * 256);
  float bias[4];
  for (int q = 0; q < 4; ++q)
    bias[q] = b_ih[p * G4_ + r0 + q] + b_hh[p * G4_ + r0 + q];

  for (int e = 0; e < NE_; ++e) {
    const float* ev = emb + (size_t)e * H_;
    float4 x[4];
    for (int it = 0; it < 4; ++it)
      x[it] = *(const float4*)(ev + lane * 4 + it * 256);
    for (int q = 0; q < 4; ++q) {
      float acc = 0.f;
      for (int it = 0; it < 4; ++it)
        acc += Wr[q][it].x * x[it].x + Wr[q][it].y * x[it].y
             + Wr[q][it].z * x[it].z + Wr[q][it].w * x[it].w;
      acc = wave_reduce_sum(acc);
      if (lane == 0)
        Xp[((size_t)p * NE_ + e) * G4_ + r0 + q] = acc + bias[q];
    }
  }
}

// warm-up: h,c from gates = Xp[p][p*33+32] (h=c=0 so W_hh term = 0, f*c = 0)
__global__ void k_warm(const float* __restrict__ Xp,
                       float* __restrict__ h, float* __restrict__ c) {
  int tid = blockIdx.x * blockDim.x + threadIdx.x;
  if (tid >= P_ * H_) return;
  int p = tid >> 10, j = tid & 1023;
  const float* g = Xp + ((size_t)p * NE_ + (p * 33 + 32)) * G4_;
  float gi = g[j], gg = g[j + 2048], go = g[j + 3072];
  float c2 = sigmoidf_(gi) * tanhf(gg);
  float h2 = sigmoidf_(go) * tanhf(c2);
  h[tid] = h2; c[tid] = c2;
}

// layer-start batched matvecs:
//   waves [0,16384):  G[p][r]            = W_hh[p][r] . h[p]
//   waves [16384,20480): anchors[4l+p][r] = w_attn1[p][r] . h[p]
__global__ __launch_bounds__(256) void k1(const float* __restrict__ w_hh,
                                          const float* __restrict__ w_attn1,
                                          const float* __restrict__ h,
                                          float* __restrict__ G,
                                          float* __restrict__ anchors,
                                          int l) {
  int wgid = blockIdx.x * 4 + (threadIdx.x >> 6);
  int lane = threadIdx.x & 63;
  const float* wrow; const float* hv; float* dst;
  if (wgid < 16384) {
    int p = wgid >> 12, r = wgid & 4095;
    wrow = w_hh + ((size_t)p * G4_ + r) * H_;
    hv   = h + p * H_;
    dst  = G + p * G4_ + r;
  } else {
    int aw = wgid - 16384;
    int p = aw >> 10, r = aw & 1023;
    wrow = w_attn1 + ((size_t)p * H_ + r) * H_;
    hv   = h + p * H_;
    dst  = anchors + (size_t)(4 * l + p) * H_ + r;
  }
  float acc = 0.f;
  for (int it = 0; it < 4; ++it) {
    float4 w4 = *(const float4*)(wrow + lane * 4 + it * 256);
    float4 h4 = *(const float4*)(hv   + lane * 4 + it * 256);
    acc += w4.x * h4.x + w4.y * h4.y + w4.z * h4.z + w4.w * h4.w;
  }
  acc = wave_reduce_sum(acc);
  if (lane == 0) *dst = acc;
}

// cell finish (redundant per block) + anchor2 = w_attn2[p] @ h'
// grid 256 blocks x 256 thr; block 0 also commits h', c' to global.
__global__ __launch_bounds__(256) void k23(const float* __restrict__ Xp,
                                           const float* __restrict__ G,
                                           const float* __restrict__ w_attn2,
                                           float* __restrict__ h,
                                           const float* __restrict__ c_in,
                                           float* __restrict__ c_out,
                                           float* __restrict__ anchor2,
                                           const int* __restrict__ idx_buf,
                                           int l, int p) {
  __shared__ __align__(16) float hsh[H_];
  int e_x;
  if (l == 0) e_x = p * 33 + 32;
  else { int idx = *idx_buf; e_x = (idx & 3) * 33 + (idx >> 2); }
  const float* xrow = Xp + ((size_t)p * NE_ + e_x) * G4_;
  const float* Gp = G + p * G4_;
  const float* cp = c_in + p * H_;
  float* hp = h + p * H_;
  float* cq = c_out + p * H_;

  for (int j = threadIdx.x; j < H_; j += 256) {
    float gi = Gp[j]        + xrow[j];
    float gf = Gp[j + 1024] + xrow[j + 1024];
    float gg = Gp[j + 2048] + xrow[j + 2048];
    float go = Gp[j + 3072] + xrow[j + 3072];
    float c2 = sigmoidf_(gf) * cp[j] + sigmoidf_(gi) * tanhf(gg);
    float h2 = sigmoidf_(go) * tanhf(c2);
    hsh[j] = h2;
    if (blockIdx.x == 0) { hp[j] = h2; cq[j] = c2; }
  }
  __syncthreads();

  int wave = threadIdx.x >> 6, lane = threadIdx.x & 63;
  int r = blockIdx.x * 4 + wave;            // 0..1023
  const float* wrow = w_attn2 + ((size_t)p * H_ + r) * H_;
  float acc = 0.f;
  for (int it = 0; it < 4; ++it) {
    float4 w4 = *(const float4*)(wrow + lane * 4 + it * 256);
    float4 h4 = *(const float4*)(&hsh[lane * 4 + it * 256]);
    acc += w4.x * h4.x + w4.y * h4.y + w4.z * h4.z + w4.w * h4.w;
  }
  acc = wave_reduce_sum(acc);
  if (lane == 0) anchor2[r] = acc;
}

// logits[i] = 2.5*tanh( (sum_d tanh(anchors[i][d]+a2[d]) * w_index[p][d]) / 5 )
__global__ __launch_bounds__(256) void k4(const float* __restrict__ anchors,
                                          const float* __restrict__ anchor2,
                                          const float* __restrict__ w_index,
                                          float* __restrict__ logits,
                                          int n, int p) {
  int wid  = blockIdx.x * 4 + (threadIdx.x >> 6);
  int lane = threadIdx.x & 63;
  if (wid >= n) return;
  const float* pq = anchors + (size_t)wid * H_;
  const float* wi = w_index + p * H_;
  float acc = 0.f;
  for (int it = 0; it < 4; ++it) {
    float4 a4 = *(const float4*)(pq      + lane * 4 + it * 256);
    float4 b4 = *(const float4*)(anchor2 + lane * 4 + it * 256);
    float4 w4 = *(const float4*)(wi      + lane * 4 + it * 256);
    acc += tanhf(a4.x + b4.x) * w4.x + tanhf(a4.y + b4.y) * w4.y
         + tanhf(a4.z + b4.z) * w4.z + tanhf(a4.w + b4.w) * w4.w;
  }
  acc = wave_reduce_sum(acc);
  if (lane == 0) logits[wid] = TANHC_ * tanhf(acc / TEMP_);
}

// sampler: Gumbel-max (bit-exact JAX threefry) + log_softmax accumulators
__global__ void k5(const float* __restrict__ logits,
                   const int* __restrict__ seed_p,
                   float* __restrict__ scalars,     // [0]=ent_acc [1]=lp_acc
                   int* __restrict__ idx_buf,
                   float* __restrict__ out,
                   int n, int t) {
  int lane = threadIdx.x;               // 0..63, one wave
  uint32_t seed = (uint32_t)(*seed_p);
  // step_key = fold_in(key=(0,seed), t) -> one block with x=(0,t)
  uint32_t sk0 = 0u, sk1 = (uint32_t)t;
  tf2x32(0u, seed, sk0, sk1);

  float sv[2], lg[2]; int ii[2];
  for (int k = 0; k < 2; ++k) {
    int i = lane + 64 * k;
    ii[k] = i;
    if (i < n) {
#if PRNG_PARTITIONABLE
      uint32_t b0 = 0u, b1 = (uint32_t)i;
      tf2x32(sk0, sk1, b0, b1);
      uint32_t bits = b0 ^ b1;
#else
      int half = n >> 1;
      uint32_t b0 = (uint32_t)(i < half ? i : i - half);
      uint32_t b1 = (uint32_t)(i < half ? i + half : i);
      uint32_t r0 = b0, r1 = b1;
      tf2x32(sk0, sk1, r0, r1);
      uint32_t bits = (i < half) ? r0 : r1;
#endif
      uint32_t fb = (bits >> 9) | 0x3F800000u;
      float u = __uint_as_float(fb) - 1.0f;          // [0,1)
      u = fmaxf(TINY_, u * (1.0f - TINY_) + TINY_);  // JAX uniform(minval=tiny)
      float g = -logf(-logf(u));
      lg[k] = logits[i];
      sv[k] = g + lg[k];
    } else { sv[k] = -INFINITY; lg[k] = -INFINITY; }
  }

  // argmax, first index wins ties
  float bv; int bi;
  if (sv[0] >= sv[1]) { bv = sv[0]; bi = ii[0]; } else { bv = sv[1]; bi = ii[1]; }
  for (int off = 32; off; off >>= 1) {
    float ov = __shfl_xor(bv, off);
    int   oi = __shfl_xor(bi, off);
    if (ov > bv || (ov == bv && oi < bi)) { bv = ov; bi = oi; }
  }

  // log_softmax pieces
  float m = fmaxf(lg[0], lg[1]);
  for (int off = 32; off; off >>= 1) m = fmaxf(m, __shfl_xor(m, off));
  float se = 0.f;
  for (int k = 0; k < 2; ++k) if (ii[k] < n) se += expf(lg[k] - m);
  se = wave_reduce_sum(se);
  float lse = logf(se);
  float ent = 0.f;
  for (int k = 0; k < 2; ++k) if (ii[k] < n) {
    float lpv = (lg[k] - m) - lse;
    ent -= expf(lpv) * lpv;
  }
  ent = wave_reduce_sum(ent);

  if (lane == 0) {
    int idx = bi;
    *idx_buf = idx;
    float lpterm = -((logits[idx] - m) - lse);
    float ea = scalars[0] + ent;
    float la = scalars[1] + lpterm;
    scalars[0] = ea; scalars[1] = la;
    out[t]        = (float)(idx & 3);   // arch % P
    out[128 + t]  = (float)(idx >> 2);  // arch // P
    out[256] = ea;                      // entropy (final overwrite wins)
    out[257] = la;                      // log_prob
  }
}

// ---------------- host ----------------
extern "C" void kernel_launch(void* const* d_in, const int* in_sizes, int n_in,
                              void* d_out, int out_size, void* d_ws, size_t ws_size,
                              hipStream_t stream) {
  (void)in_sizes; (void)n_in; (void)out_size; (void)ws_size;
  const float* emb   = (const float*)d_in[0];
  const float* w_ih  = (const float*)d_in[1];
  const float* w_hh  = (const float*)d_in[2];
  const float* b_ih  = (const float*)d_in[3];
  const float* b_hh  = (const float*)d_in[4];
  const float* w_a1  = (const float*)d_in[5];
  const float* w_a2  = (const float*)d_in[6];
  const float* w_idx = (const float*)d_in[7];
  const int*   seed  = (const int*)d_in[8];
  float* out = (float*)d_out;

  float* ws = (float*)d_ws;
  size_t o = 0;
  float* Xp      = ws + o; o += (size_t)P_ * NE_ * G4_;  // 2,162,688
  float* G       = ws + o; o += (size_t)P_ * G4_;        // 16,384
  float* h       = ws + o; o += (size_t)P_ * H_;         // 4,096
  float* c0      = ws + o; o += (size_t)P_ * H_;
  float* c1      = ws + o; o += (size_t)P_ * H_;
  float* anchors = ws + o; o += (size_t)128 * H_;        // 131,072
  float* anchor2 = ws + o; o += H_;
  float* logits  = ws + o; o += 128;
  float* scalars = ws + o; o += 64;
  int*   idx_buf = (int*)(ws + o);

  k_init<<<1, 64, 0, stream>>>(scalars, idx_buf);
  k_pre <<<1024, 256, 0, stream>>>(emb, w_ih, b_ih, b_hh, Xp);
  k_warm<<<16, 256, 0, stream>>>(Xp, h, c0);

  for (int l = 0; l < L_; ++l) {
    k1<<<5120, 256, 0, stream>>>(w_hh, w_a1, h, G, anchors, l);
    const float* c_in  = (l & 1) ? c1 : c0;
    float*       c_out = (l & 1) ? c0 : c1;
    int n = 4 * (l + 1);
    for (int p = 0; p < P_; ++p) {
      k23<<<256, 256, 0, stream>>>(Xp, G, w_a2, h, c_in, c_out, anchor2,
                                   idx_buf, l, p);
      k4<<<32, 256, 0, stream>>>(anchors, anchor2, w_idx, logits, n, p);
      k5<<<1, 64, 0, stream>>>(logits, seed, scalars, idx_buf, out, n, 4 * l + p);
    }
  }
}